// Round 4
// baseline (240.241 us; speedup 1.0000x reference)
//
#include <hip/hip_runtime.h>
#include <hip/hip_bf16.h>

// Shapes (fixed by the problem)
#define BATCH 8
#define SEQ   2048
#define DM    768
#define DD    64   // DK == DV == 64
#define NSPLIT 4
#define SPLIT_S (SEQ / NSPLIT)   // 512
#define BS (BATCH * SEQ)         // 16384

typedef __bf16 bf16x8 __attribute__((ext_vector_type(8)));
typedef float  f32x4  __attribute__((ext_vector_type(4)));
typedef short  short8 __attribute__((ext_vector_type(8)));
typedef short  short4v __attribute__((ext_vector_type(4)));

#define MFMA16(a, b, c) __builtin_amdgcn_mfma_f32_16x16x32_bf16((a), (b), (c), 0, 0, 0)

__device__ __forceinline__ short f2bf(float x) {
    unsigned u = __builtin_bit_cast(unsigned, x);
    u = (u + 0x7fffu + ((u >> 16) & 1u)) >> 16;   // round-to-nearest-even
    return (short)u;
}
__device__ __forceinline__ float bf2f(short s) {
    unsigned u = ((unsigned)(unsigned short)s) << 16;
    return __builtin_bit_cast(float, u);
}
__device__ __forceinline__ bf16x8 cvt8(float4 a, float4 b) {
    bf16x8 r;
    r[0] = (__bf16)a.x; r[1] = (__bf16)a.y; r[2] = (__bf16)a.z; r[3] = (__bf16)a.w;
    r[4] = (__bf16)b.x; r[5] = (__bf16)b.y; r[6] = (__bf16)b.z; r[7] = (__bf16)b.w;
    return r;
}

// ---------------------------------------------------------------------------
// Kernel 1: W [768][64] f32 -> Wt [3][64][768] bf16 (transposed, n-major).
// Wq pre-scaled by 1/8 (the 1/sqrt(DK) of the scores).
// ---------------------------------------------------------------------------
__global__ void prep_w_kernel(const float* __restrict__ Wq, const float* __restrict__ Wk,
                              const float* __restrict__ Wv, short* __restrict__ Wt) {
    int idx = blockIdx.x * 256 + threadIdx.x;
    if (idx >= 3 * DM * DD) return;
    int m = idx / (DM * DD);
    int r = (idx % (DM * DD)) / DD;
    int c = idx % DD;
    const float* W = (m == 0) ? Wq : (m == 1) ? Wk : Wv;
    float scale = (m == 0) ? 0.125f : 1.0f;
    Wt[m * DM * DD + c * DM + r] = f2bf(W[r * DD + c] * scale);
}

// ---------------------------------------------------------------------------
// Kernel 2: projections, 1 wave/block, 16 rows/wave, depth-2 x-prefetch
// (k-step 64 => 4 KB/wave HBM bytes in flight). blocks [0,1024): Q from x1.
// blocks [1024,2048): K AND V from x2 (x2 read once). V stored transposed
// [b][v][s] + fused column-sum C[b][v] via f32 atomics.
// ---------------------------------------------------------------------------
__global__ __launch_bounds__(64) void proj_kernel(
        const float* __restrict__ x1, const float* __restrict__ x2,
        const short* __restrict__ Wt,
        const float* __restrict__ bq, const float* __restrict__ bk,
        const float* __restrict__ bv,
        short* __restrict__ Qs, short* __restrict__ Kb, short* __restrict__ Vtb,
        float* __restrict__ C) {
    const int lane = threadIdx.x, quad = lane >> 4, l15 = lane & 15;
    const int m  = blockIdx.x >> 10;          // 0=Q, 1=K+V
    const int r0 = (blockIdx.x & 1023) * 16;

    const float* xp = ((m == 0) ? x1 : x2) + (size_t)(r0 + l15) * DM + quad * 8;
    const short* wpa = Wt + (size_t)m * DM * DD + (size_t)l15 * DM + quad * 8;       // Wq or Wk
    const short* wpv = Wt + 2 * (size_t)DM * DD + (size_t)l15 * DM + quad * 8;       // Wv

    f32x4 acc0[4] = {}, acc1[4] = {};
    float4 xa0 = *(const float4*)xp;
    float4 xb0 = *(const float4*)(xp + 4);
    float4 xa1 = *(const float4*)(xp + 32);
    float4 xb1 = *(const float4*)(xp + 36);

    if (m == 0) {
#pragma unroll
        for (int k0 = 0; k0 < DM; k0 += 64) {
            const int kp1 = (k0 + 64 < DM) ? k0 + 64 : DM - 32;
            const int kp2 = (k0 + 96 < DM) ? k0 + 96 : DM - 32;
            float4 na0 = *(const float4*)(xp + kp1);
            float4 nb0 = *(const float4*)(xp + kp1 + 4);
            float4 na1 = *(const float4*)(xp + kp2);
            float4 nb1 = *(const float4*)(xp + kp2 + 4);
            bf16x8 af = cvt8(xa0, xb0);
#pragma unroll
            for (int tn = 0; tn < 4; tn++)
                acc0[tn] = MFMA16(af, *(const bf16x8*)(wpa + (size_t)tn * 16 * DM + k0), acc0[tn]);
            af = cvt8(xa1, xb1);
#pragma unroll
            for (int tn = 0; tn < 4; tn++)
                acc0[tn] = MFMA16(af, *(const bf16x8*)(wpa + (size_t)tn * 16 * DM + k0 + 32), acc0[tn]);
            xa0 = na0; xb0 = nb0; xa1 = na1; xb1 = nb1;
        }
#pragma unroll
        for (int tn = 0; tn < 4; tn++) {
            int v = tn * 16 + l15;
            float bb = bq[v] * 0.125f;
#pragma unroll
            for (int r = 0; r < 4; r++)
                Qs[(size_t)(r0 + quad * 4 + r) * DD + v] = f2bf(acc0[tn][r] + bb);
        }
    } else {
#pragma unroll
        for (int k0 = 0; k0 < DM; k0 += 64) {
            const int kp1 = (k0 + 64 < DM) ? k0 + 64 : DM - 32;
            const int kp2 = (k0 + 96 < DM) ? k0 + 96 : DM - 32;
            float4 na0 = *(const float4*)(xp + kp1);
            float4 nb0 = *(const float4*)(xp + kp1 + 4);
            float4 na1 = *(const float4*)(xp + kp2);
            float4 nb1 = *(const float4*)(xp + kp2 + 4);
            bf16x8 af = cvt8(xa0, xb0);
#pragma unroll
            for (int tn = 0; tn < 4; tn++) {
                acc0[tn] = MFMA16(af, *(const bf16x8*)(wpa + (size_t)tn * 16 * DM + k0), acc0[tn]);
                acc1[tn] = MFMA16(af, *(const bf16x8*)(wpv + (size_t)tn * 16 * DM + k0), acc1[tn]);
            }
            af = cvt8(xa1, xb1);
#pragma unroll
            for (int tn = 0; tn < 4; tn++) {
                acc0[tn] = MFMA16(af, *(const bf16x8*)(wpa + (size_t)tn * 16 * DM + k0 + 32), acc0[tn]);
                acc1[tn] = MFMA16(af, *(const bf16x8*)(wpv + (size_t)tn * 16 * DM + k0 + 32), acc1[tn]);
            }
            xa0 = na0; xb0 = nb0; xa1 = na1; xb1 = nb1;
        }
#pragma unroll
        for (int tn = 0; tn < 4; tn++) {
            int v = tn * 16 + l15;
            float bb = bk[v];
#pragma unroll
            for (int r = 0; r < 4; r++)
                Kb[(size_t)(r0 + quad * 4 + r) * DD + v] = f2bf(acc0[tn][r] + bb);
        }
        const int b = r0 / SEQ;
        const int sbase = (r0 % SEQ) + quad * 4;
#pragma unroll
        for (int tn = 0; tn < 4; tn++) {
            int v = tn * 16 + l15;
            float bb = bv[v];
            short4v pk;
            float cs = 0.f;
#pragma unroll
            for (int r = 0; r < 4; r++) {
                pk[r] = f2bf(acc1[tn][r] + bb);
                cs += bf2f(pk[r]);           // sum the rounded values (consistency)
            }
            *(short4v*)(Vtb + ((size_t)b * DD + v) * SEQ + sbase) = pk;
            cs += __shfl_xor(cs, 16);
            cs += __shfl_xor(cs, 32);
            if (quad == 0) atomicAdd(&C[b * DD + v], cs);
        }
    }
}

// ---------------------------------------------------------------------------
// Kernel 3: flash partial — ZERO barriers. K/V MFMA fragments read directly
// from global (L2/L3-resident: K+V = 4 MB total); per-wave LDS buffer only
// for the P^T transpose (no cross-wave access => no __syncthreads).
// grid (32 q-tiles, 8 batches, NSPLIT); block 256 = 4 waves x 16 q-rows.
// Z^T = K.Q^T (A=K, B=Q): C-layout q=l15, s=tn*16+quad*4+r -> b64 P writes.
// Y^T = V^T.P^T: q=l15, v=tn*16+quad*4+r. Emits unnormalized Yp + den Dp.
// ---------------------------------------------------------------------------
#define PSTR 88   // 176 B row: 16B-aligned b128 reads ~2-way, b64 writes 2-way
__global__ __launch_bounds__(256) void flash_kernel(
        const short* __restrict__ Q, const short* __restrict__ K,
        const short* __restrict__ Vt,
        short* __restrict__ Yp, float* __restrict__ Dp) {
    __shared__ __align__(16) short pb[4][16 * PSTR];  // per-wave P^T [q][s]
    const int tid  = threadIdx.x;
    const int wave = tid >> 6, lane = tid & 63, quad = lane >> 4, l15 = lane & 15;
    const int b = blockIdx.y, q0 = blockIdx.x * 64, split = blockIdx.z;

    // Q as B-operand: n=l15 -> q-row = q0+wave*16+l15; k = d = quad*8+j
    const short* Qp = Q + ((size_t)(b * SEQ + q0) + wave * 16 + l15) * DD;
    bf16x8 qb0 = *(const bf16x8*)(Qp + quad * 8);
    bf16x8 qb1 = *(const bf16x8*)(Qp + 32 + quad * 8);

    const short* Kp = K  + (size_t)b * SEQ * DD + (size_t)l15 * DD + quad * 8;
    const short* Vp = Vt + (size_t)b * DD * SEQ + (size_t)l15 * SEQ + quad * 8;
    f32x4 y[4] = {};
    float den = 0.f;
    short* pw = &pb[wave][0];

    const int send = split * SPLIT_S + SPLIT_S;
    for (int s0 = split * SPLIT_S; s0 < send; s0 += 64) {
        // Z^T = K.Q^T per s-subtile tn (A-frag rows = s = tn*16+l15)
#pragma unroll
        for (int tn = 0; tn < 4; tn++) {
            const short* kf = Kp + (size_t)(s0 + tn * 16) * DD;
            bf16x8 ka0 = *(const bf16x8*)(kf);
            bf16x8 ka1 = *(const bf16x8*)(kf + 32);
            f32x4 z = {0.f, 0.f, 0.f, 0.f};
            z = MFMA16(ka0, qb0, z);
            z = MFMA16(ka1, qb1, z);
            short4v pk;
#pragma unroll
            for (int r = 0; r < 4; r++) {
                float p = __expf(z[r]);
                den += p;
                pk[r] = f2bf(p);
            }
            *(short4v*)&pw[l15 * PSTR + tn * 16 + quad * 4] = pk;  // P^T[q][s]
        }
        // Y^T += V^T.P^T  (A-frag rows = v = tn*16+l15, k = s)
#pragma unroll
        for (int kc = 0; kc < 2; kc++) {
            bf16x8 pB = *(const bf16x8*)&pw[l15 * PSTR + kc * 32 + quad * 8];
#pragma unroll
            for (int tn = 0; tn < 4; tn++) {
                bf16x8 va = *(const bf16x8*)(Vp + (size_t)(tn * 16) * SEQ + s0 + kc * 32);
                y[tn] = MFMA16(va, pB, y[tn]);
            }
        }
    }
    // den: per-lane covers an s-subset for q=l15; sum across the 4 quads
    den += __shfl_xor(den, 16);
    den += __shfl_xor(den, 32);
    const int qrow = b * SEQ + q0 + wave * 16 + l15;
    size_t ybase = (size_t)split * BS * DD + (size_t)qrow * DD;
#pragma unroll
    for (int tn = 0; tn < 4; tn++) {
        short4v pk;
#pragma unroll
        for (int r = 0; r < 4; r++) pk[r] = f2bf(y[tn][r]);
        *(short4v*)(Yp + ybase + tn * 16 + quad * 4) = pk;
    }
    if (quad == 0) Dp[split * BS + qrow] = den;
}

// ---------------------------------------------------------------------------
// Kernel 4: combine splits + reverse transform + LayerNorm. One wave/q-row.
// ---------------------------------------------------------------------------
__global__ __launch_bounds__(256) void reduce_ln_kernel(
        const short* __restrict__ Yp, const float* __restrict__ Dp,
        const float* __restrict__ C, const float* __restrict__ gamma,
        const float* __restrict__ beta, float* __restrict__ out) {
    const int row = blockIdx.x * 4 + (threadIdx.x >> 6);
    const int v = threadIdx.x & 63;
    const int b = row >> 11;
    float Y = 0.f, D = 0.f;
#pragma unroll
    for (int s = 0; s < NSPLIT; s++) {
        Y += bf2f(Yp[((size_t)s * BS + row) * DD + v]);
        D += Dp[s * BS + row];
    }
    float attn = (C[b * DD + v] - Y / D) * (1.0f / (float)(SEQ - 1));
    float msum = attn, ssum = attn * attn;
#pragma unroll
    for (int m = 1; m < 64; m <<= 1) {
        msum += __shfl_xor(msum, m);
        ssum += __shfl_xor(ssum, m);
    }
    float mu = msum * (1.0f / 64.0f);
    float var = ssum * (1.0f / 64.0f) - mu * mu;
    float rs = rsqrtf(var + 1e-5f);
    out[(size_t)row * DD + v] = (attn - mu) * rs * gamma[v] + beta[v];
}

// ---------------------------------------------------------------------------
extern "C" void kernel_launch(void* const* d_in, const int* in_sizes, int n_in,
                              void* d_out, int out_size, void* d_ws, size_t ws_size,
                              hipStream_t stream) {
    const float* x1    = (const float*)d_in[0];
    const float* x2    = (const float*)d_in[1];
    const float* Wq    = (const float*)d_in[2];
    const float* bq    = (const float*)d_in[3];
    const float* Wk    = (const float*)d_in[4];
    const float* bk    = (const float*)d_in[5];
    const float* Wv    = (const float*)d_in[6];
    const float* bv    = (const float*)d_in[7];
    const float* gamma = (const float*)d_in[8];
    const float* beta  = (const float*)d_in[9];
    float* out = (float*)d_out;

    char* ws = (char*)d_ws;
    short* Qs  = (short*)(ws);                         // 2 MB  bf16 [16384][64]
    short* Kbf = (short*)(ws + (2ull << 20));          // 2 MB  bf16 [16384][64]
    short* Vtb = (short*)(ws + (4ull << 20));          // 2 MB  bf16 [8][64][2048]
    short* Wt  = (short*)(ws + (6ull << 20));          // 288 KB bf16 [3][64][768]
    float* Cc  = (float*)(ws + (6ull << 20) + 3 * DM * DD * 2);  // 2 KB f32 [8][64]
    short* Yp  = (short*)(ws + (7ull << 20));          // 8 MB  bf16 [NSPLIT][16384][64]
    float* Dp  = (float*)(ws + (16ull << 20));         // 256 KB f32 [NSPLIT][16384]

    hipMemsetAsync(Cc, 0, BATCH * DD * sizeof(float), stream);
    prep_w_kernel<<<576, 256, 0, stream>>>(Wq, Wk, Wv, Wt);
    proj_kernel<<<2048, 64, 0, stream>>>(x1, x2, Wt, bq, bk, bv, Qs, Kbf, Vtb, Cc);
    flash_kernel<<<dim3(32, 8, NSPLIT), 256, 0, stream>>>(Qs, Kbf, Vtb, Yp, Dp);
    reduce_ln_kernel<<<BS / 4, 256, 0, stream>>>(Yp, Dp, Cc, gamma, beta, out);
}

// Round 5
// 173.058 us; speedup vs baseline: 1.3882x; 1.3882x over previous
//
#include <hip/hip_runtime.h>
#include <hip/hip_bf16.h>

// Shapes (fixed by the problem)
#define BATCH 8
#define SEQ   2048
#define DM    768
#define DD    64   // DK == DV == 64
#define BS (BATCH * SEQ)         // 16384
#define SCALEQ 0.1803369380478f  // (1/8) * log2(e): score in log2 domain

typedef __bf16 bf16x8 __attribute__((ext_vector_type(8)));
typedef float  f32x4  __attribute__((ext_vector_type(4)));
typedef short  short8 __attribute__((ext_vector_type(8)));
typedef short  short4v __attribute__((ext_vector_type(4)));

#define MFMA16(a, b, c) __builtin_amdgcn_mfma_f32_16x16x32_bf16((a), (b), (c), 0, 0, 0)

__device__ __forceinline__ short f2bf(float x) {
    unsigned u = __builtin_bit_cast(unsigned, x);
    u = (u + 0x7fffu + ((u >> 16) & 1u)) >> 16;   // round-to-nearest-even
    return (short)u;
}
__device__ __forceinline__ float bf2f(short s) {
    unsigned u = ((unsigned)(unsigned short)s) << 16;
    return __builtin_bit_cast(float, u);
}
__device__ __forceinline__ bf16x8 cvt8v(f32x4 a, f32x4 b) {
    bf16x8 r;
    r[0] = (__bf16)a[0]; r[1] = (__bf16)a[1]; r[2] = (__bf16)a[2]; r[3] = (__bf16)a[3];
    r[4] = (__bf16)b[0]; r[5] = (__bf16)b[1]; r[6] = (__bf16)b[2]; r[7] = (__bf16)b[3];
    return r;
}
__device__ __forceinline__ void glds16(const void* g, void* l) {
    __builtin_amdgcn_global_load_lds(
        (const __attribute__((address_space(1))) void*)g,
        (__attribute__((address_space(3))) void*)l, 16, 0, 0);
}

// ---------------------------------------------------------------------------
// Kernel 1: W [768][64] f32 -> Wt [3][64][768] bf16 (transposed, n-major).
// Wq pre-scaled by (1/8)*log2e so flash can use raw v_exp_f32 (2^x).
// ---------------------------------------------------------------------------
__global__ void prep_w_kernel(const float* __restrict__ Wq, const float* __restrict__ Wk,
                              const float* __restrict__ Wv, short* __restrict__ Wt) {
    int idx = blockIdx.x * 256 + threadIdx.x;
    if (idx >= 3 * DM * DD) return;
    int m = idx / (DM * DD);
    int r = (idx % (DM * DD)) / DD;
    int c = idx % DD;
    const float* W = (m == 0) ? Wq : (m == 1) ? Wk : Wv;
    float scale = (m == 0) ? SCALEQ : 1.0f;
    Wt[m * DM * DD + c * DM + r] = f2bf(W[r * DD + c] * scale);
}

// ---------------------------------------------------------------------------
// Kernel 2: projections, m97-style: 64-row tiles, double-buffered LDS fed by
// global_load_lds width=16, XOR piece-swizzle for conflict-free b128 reads.
// blocks [0,256): Q from x1; blocks [256,512): K AND V from x2 (read once).
// V stored transposed [b][v][s] + fused column-sum C via f32 atomics.
// LDS: x 2x16KB (f32) + W 2x2x8KB (bf16) = 64KB -> 2 blocks/CU.
// ---------------------------------------------------------------------------
__global__ __launch_bounds__(256) void proj_kernel(
        const float* __restrict__ x1, const float* __restrict__ x2,
        const short* __restrict__ Wt,
        const float* __restrict__ bq, const float* __restrict__ bk,
        const float* __restrict__ bv,
        short* __restrict__ Qs, short* __restrict__ Kb, short* __restrict__ Vtb,
        float* __restrict__ C) {
    __shared__ __align__(16) float xl[2][64 * 64];     // [buf][row][16 pieces x 4f]
    __shared__ __align__(16) short wl[2][2][64 * 64];  // [buf][mat][row][8 pieces x 8h]
    const int tid = threadIdx.x, wave = tid >> 6, lane = tid & 63;
    const int quad = lane >> 4, l15 = lane & 15;
    const int kv = blockIdx.x >> 8;            // 0 = Q, 1 = K+V
    const int r0 = (blockIdx.x & 255) * 64;
    const float* x = kv ? x2 : x1;
    const short* W0 = Wt + (kv ? (size_t)(DM * DD) : 0);
    const short* W1 = Wt + 2 * (size_t)(DM * DD);

    const int xri = lane >> 4, xsl = lane & 15;   // x-stage: 4 rows x 16 pieces
    const int wri = lane >> 3, wsl = lane & 7;    // w-stage: 8 rows x 8 pieces

    f32x4 acc0[4] = {}, acc1[4] = {};

    // preload tile 0
    {
#pragma unroll
        for (int j = 0; j < 4; j++) {
            int rl = wave * 16 + j * 4 + xri;
            int piece = xsl ^ (rl & 7);
            glds16(x + (size_t)(r0 + rl) * DM + piece * 4, &xl[0][(wave * 16 + j * 4) * 64]);
        }
#pragma unroll
        for (int t = 0; t < 2; t++) {
            int rl = wave * 16 + t * 8 + wri;
            int piece = wsl ^ (rl & 7);
            glds16(W0 + (size_t)rl * DM + piece * 8, &wl[0][0][(wave * 16 + t * 8) * 64]);
            if (kv)
                glds16(W1 + (size_t)rl * DM + piece * 8, &wl[0][1][(wave * 16 + t * 8) * 64]);
        }
    }
    __syncthreads();

    const int sw = l15 & 7;
    const int arow = (wave * 16 + l15) * 64;
    for (int it = 0; it < 12; it++) {
        const int buf = it & 1;
        if (it < 11) {
            const int k0 = (it + 1) * 64;
#pragma unroll
            for (int j = 0; j < 4; j++) {
                int rl = wave * 16 + j * 4 + xri;
                int piece = xsl ^ (rl & 7);
                glds16(x + (size_t)(r0 + rl) * DM + k0 + piece * 4,
                       &xl[buf ^ 1][(wave * 16 + j * 4) * 64]);
            }
#pragma unroll
            for (int t = 0; t < 2; t++) {
                int rl = wave * 16 + t * 8 + wri;
                int piece = wsl ^ (rl & 7);
                glds16(W0 + (size_t)rl * DM + k0 + piece * 8,
                       &wl[buf ^ 1][0][(wave * 16 + t * 8) * 64]);
                if (kv)
                    glds16(W1 + (size_t)rl * DM + k0 + piece * 8,
                           &wl[buf ^ 1][1][(wave * 16 + t * 8) * 64]);
            }
        }
        // compute on current buffer
#pragma unroll
        for (int kc = 0; kc < 2; kc++) {
            f32x4 a0 = *(const f32x4*)&xl[buf][arow + ((kc * 8 + quad * 2) ^ sw) * 4];
            f32x4 a1 = *(const f32x4*)&xl[buf][arow + ((kc * 8 + quad * 2 + 1) ^ sw) * 4];
            bf16x8 af = cvt8v(a0, a1);
#pragma unroll
            for (int tn = 0; tn < 4; tn++) {
                bf16x8 b0 = *(const bf16x8*)&wl[buf][0][(tn * 16 + l15) * 64 + ((kc * 4 + quad) ^ sw) * 8];
                acc0[tn] = MFMA16(af, b0, acc0[tn]);
                if (kv) {
                    bf16x8 b1 = *(const bf16x8*)&wl[buf][1][(tn * 16 + l15) * 64 + ((kc * 4 + quad) ^ sw) * 8];
                    acc1[tn] = MFMA16(af, b1, acc1[tn]);
                }
            }
        }
        __syncthreads();
    }

    if (!kv) {
#pragma unroll
        for (int tn = 0; tn < 4; tn++) {
            int v = tn * 16 + l15;
            float bb = bq[v] * SCALEQ;
#pragma unroll
            for (int r = 0; r < 4; r++)
                Qs[(size_t)(r0 + wave * 16 + quad * 4 + r) * DD + v] = f2bf(acc0[tn][r] + bb);
        }
    } else {
#pragma unroll
        for (int tn = 0; tn < 4; tn++) {
            int v = tn * 16 + l15;
            float bb = bk[v];
#pragma unroll
            for (int r = 0; r < 4; r++)
                Kb[(size_t)(r0 + wave * 16 + quad * 4 + r) * DD + v] = f2bf(acc0[tn][r] + bb);
        }
        const int b = r0 / SEQ;
        const int sbase = (r0 % SEQ) + wave * 16 + quad * 4;
#pragma unroll
        for (int tn = 0; tn < 4; tn++) {
            int v = tn * 16 + l15;
            float bb = bv[v];
            short4v pk;
            float cs = 0.f;
#pragma unroll
            for (int r = 0; r < 4; r++) {
                pk[r] = f2bf(acc1[tn][r] + bb);
                cs += bf2f(pk[r]);           // sum the rounded values (consistency)
            }
            *(short4v*)(Vtb + ((size_t)b * DD + v) * SEQ + sbase) = pk;
            cs += __shfl_xor(cs, 16);
            cs += __shfl_xor(cs, 32);
            if (quad == 0) atomicAdd(&C[b * DD + v], cs);
        }
    }
}

// ---------------------------------------------------------------------------
// Kernel 3: flash partial — waves own DISJOINT s-quarters (no intra-block K/V
// read duplication); each wave computes all 64 q over its 256 s. XCD-affine:
// b = blockIdx & 7 pins each batch's K/V (512 KB) to one XCD L2.
// Z^T = K.Q^T (log2 domain, exp2 via v_exp_f32). Intra-block 4-way split
// reduction through LDS; emits 2 global splits (halves) Yp bf16 + Dp f32.
// ---------------------------------------------------------------------------
#define PBS 72   // pbuf row stride (shorts)
__global__ __launch_bounds__(256, 2) void flash_kernel(
        const short* __restrict__ Q, const short* __restrict__ K,
        const short* __restrict__ Vt,
        short* __restrict__ Yp, float* __restrict__ Dp) {
    __shared__ __align__(16) short pbuf[4][64 * PBS];  // per-wave P^T [q][s] / y-partials
    __shared__ float dl[4][64];
    const int tid  = threadIdx.x;
    const int wave = tid >> 6, lane = tid & 63, quad = lane >> 4, l15 = lane & 15;
    const int blk = blockIdx.x;
    const int b = blk & 7, qt = (blk >> 3) & 31, half = blk >> 8;
    const int q0 = qt * 64;

    // Q fragments (B-operand): [qn][kc], n=l15 -> q = q0+qn*16+l15, k=kc*32+quad*8+j
    bf16x8 qf[4][2];
#pragma unroll
    for (int qn = 0; qn < 4; qn++)
#pragma unroll
        for (int kc = 0; kc < 2; kc++)
            qf[qn][kc] = *(const bf16x8*)(Q + ((size_t)(b * SEQ + q0 + qn * 16 + l15)) * DD + kc * 32 + quad * 8);

    const short* Kbp = K  + (size_t)b * SEQ * DD;
    const short* Vbp = Vt + (size_t)b * DD * SEQ;
    f32x4 y[4][4] = {};          // [qn][vn]
    float den[4] = {0.f, 0.f, 0.f, 0.f};
    short* pw = &pbuf[wave][0];

    const int s_begin = half * 1024 + wave * 256;
    for (int s0 = s_begin; s0 < s_begin + 256; s0 += 64) {
        // Z^T = K.Q^T  (A = K rows s, B = Q)
#pragma unroll
        for (int tn = 0; tn < 4; tn++) {
            const short* kf = Kbp + (size_t)(s0 + tn * 16 + l15) * DD + quad * 8;
            bf16x8 ka0 = *(const bf16x8*)kf;
            bf16x8 ka1 = *(const bf16x8*)(kf + 32);
#pragma unroll
            for (int qn = 0; qn < 4; qn++) {
                f32x4 z = {0.f, 0.f, 0.f, 0.f};
                z = MFMA16(ka0, qf[qn][0], z);
                z = MFMA16(ka1, qf[qn][1], z);
                short4v pk;
#pragma unroll
                for (int r = 0; r < 4; r++) {
                    float p = __builtin_amdgcn_exp2f(z[r]);
                    den[qn] += p;
                    pk[r] = f2bf(p);
                }
                // P^T[q = qn*16+l15][s_local = tn*16+quad*4 .. +3]
                *(short4v*)&pw[(qn * 16 + l15) * PBS + tn * 16 + quad * 4] = pk;
            }
        }
        // Y^T += V^T.P^T
#pragma unroll
        for (int kc = 0; kc < 2; kc++) {
            bf16x8 pB[4];
#pragma unroll
            for (int qn = 0; qn < 4; qn++)
                pB[qn] = *(const bf16x8*)&pw[(qn * 16 + l15) * PBS + kc * 32 + quad * 8];
#pragma unroll
            for (int vn = 0; vn < 4; vn++) {
                bf16x8 va = *(const bf16x8*)(Vbp + (size_t)(vn * 16 + l15) * SEQ + s0 + kc * 32 + quad * 8);
#pragma unroll
                for (int qn = 0; qn < 4; qn++)
                    y[qn][vn] = MFMA16(va, pB[qn], y[qn][vn]);
            }
        }
    }
    // complete den (each lane had quad's s-subset)
#pragma unroll
    for (int qn = 0; qn < 4; qn++) {
        den[qn] += __shfl_xor(den[qn], 16);
        den[qn] += __shfl_xor(den[qn], 32);
    }
    // write wave partials into own pbuf region [q][v] (bf16) + dl
#pragma unroll
    for (int qn = 0; qn < 4; qn++) {
#pragma unroll
        for (int vn = 0; vn < 4; vn++) {
            short4v pk;
#pragma unroll
            for (int r = 0; r < 4; r++) pk[r] = f2bf(y[qn][vn][r]);
            *(short4v*)&pw[(qn * 16 + l15) * PBS + vn * 16 + quad * 4] = pk;
        }
        if (quad == 0) dl[wave][qn * 16 + l15] = den[qn];
    }
    __syncthreads();
    // cross-wave reduce: wave handles q = wave*16+l15; quad covers v = quad*16..+15
    {
        const int q = wave * 16 + l15;
        float D = dl[0][q] + dl[1][q] + dl[2][q] + dl[3][q];
        float ys[16];
#pragma unroll
        for (int j = 0; j < 16; j++) ys[j] = 0.f;
#pragma unroll
        for (int u = 0; u < 4; u++) {
#pragma unroll
            for (int h = 0; h < 2; h++) {
                bf16x8 t = *(const bf16x8*)&pbuf[u][q * PBS + quad * 16 + h * 8];
#pragma unroll
                for (int j = 0; j < 8; j++) ys[h * 8 + j] += (float)t[j];
            }
        }
        const size_t row = (size_t)b * SEQ + q0 + q;
        short8 o0, o1;
#pragma unroll
        for (int j = 0; j < 8; j++) { o0[j] = f2bf(ys[j]); o1[j] = f2bf(ys[8 + j]); }
        short* yout = Yp + ((size_t)half * BS + row) * DD + quad * 16;
        *(short8*)yout = o0;
        *(short8*)(yout + 8) = o1;
        if (quad == 0) Dp[half * BS + row] = D;
    }
}

// ---------------------------------------------------------------------------
// Kernel 4: combine 2 halves + reverse transform + LayerNorm. One wave/q-row.
// ---------------------------------------------------------------------------
__global__ __launch_bounds__(256) void reduce_ln_kernel(
        const short* __restrict__ Yp, const float* __restrict__ Dp,
        const float* __restrict__ C, const float* __restrict__ gamma,
        const float* __restrict__ beta, float* __restrict__ out) {
    const int row = blockIdx.x * 4 + (threadIdx.x >> 6);
    const int v = threadIdx.x & 63;
    const int b = row >> 11;
    float Y = bf2f(Yp[(size_t)row * DD + v]) + bf2f(Yp[((size_t)BS + row) * DD + v]);
    float D = Dp[row] + Dp[BS + row];
    float attn = (C[b * DD + v] - Y / D) * (1.0f / (float)(SEQ - 1));
    float msum = attn, ssum = attn * attn;
#pragma unroll
    for (int m = 1; m < 64; m <<= 1) {
        msum += __shfl_xor(msum, m);
        ssum += __shfl_xor(ssum, m);
    }
    float mu = msum * (1.0f / 64.0f);
    float var = ssum * (1.0f / 64.0f) - mu * mu;
    float rs = rsqrtf(var + 1e-5f);
    out[(size_t)row * DD + v] = (attn - mu) * rs * gamma[v] + beta[v];
}

// ---------------------------------------------------------------------------
extern "C" void kernel_launch(void* const* d_in, const int* in_sizes, int n_in,
                              void* d_out, int out_size, void* d_ws, size_t ws_size,
                              hipStream_t stream) {
    const float* x1    = (const float*)d_in[0];
    const float* x2    = (const float*)d_in[1];
    const float* Wq    = (const float*)d_in[2];
    const float* bq    = (const float*)d_in[3];
    const float* Wk    = (const float*)d_in[4];
    const float* bk    = (const float*)d_in[5];
    const float* Wv    = (const float*)d_in[6];
    const float* bv    = (const float*)d_in[7];
    const float* gamma = (const float*)d_in[8];
    const float* beta  = (const float*)d_in[9];
    float* out = (float*)d_out;

    char* ws = (char*)d_ws;
    short* Qs  = (short*)(ws);                         // 2 MB  bf16 [16384][64]
    short* Kbf = (short*)(ws + (2ull << 20));          // 2 MB  bf16 [16384][64]
    short* Vtb = (short*)(ws + (4ull << 20));          // 2 MB  bf16 [8][64][2048]
    short* Wt  = (short*)(ws + (6ull << 20));          // 288 KB bf16 [3][64][768]
    float* Cc  = (float*)(ws + (6ull << 20) + 3 * DM * DD * 2);  // 2 KB f32 [8][64]
    short* Yp  = (short*)(ws + (7ull << 20));          // 4 MB  bf16 [2][16384][64]
    float* Dp  = (float*)(ws + (11ull << 20));         // 128 KB f32 [2][16384]

    hipMemsetAsync(Cc, 0, BATCH * DD * sizeof(float), stream);
    prep_w_kernel<<<576, 256, 0, stream>>>(Wq, Wk, Wv, Wt);
    proj_kernel<<<512, 256, 0, stream>>>(x1, x2, Wt, bq, bk, bv, Qs, Kbf, Vtb, Cc);
    flash_kernel<<<512, 256, 0, stream>>>(Qs, Kbf, Vtb, Yp, Dp);
    reduce_ln_kernel<<<BS / 4, 256, 0, stream>>>(Yp, Dp, Cc, gamma, beta, out);
}